// Round 16
// baseline (174.385 us; speedup 1.0000x reference)
//
#include <hip/hip_runtime.h>

typedef unsigned short u16;
typedef short bf16x8 __attribute__((ext_vector_type(8)));
typedef short bf16x4 __attribute__((ext_vector_type(4)));
typedef float f32x4 __attribute__((ext_vector_type(4)));
typedef unsigned u32x4 __attribute__((ext_vector_type(4)));
typedef unsigned short u16x4 __attribute__((ext_vector_type(4)));

#define HID 768
#define NH  12
#define HD  64
#define BB  16
#define SEQ 512
#define TOK (BB*SEQ)   // 8192 tokens

static __device__ __forceinline__ u16 f2bf(float f){
  union { float f; unsigned u; } x; x.f = f;
  unsigned r = x.u + 0x7fffu + ((x.u >> 16) & 1u);   // RNE
  return (u16)(r >> 16);
}
static __device__ __forceinline__ float bf2f(u16 h){
  return __builtin_bit_cast(float, ((unsigned)h) << 16);
}

static __device__ __forceinline__ void gl_lds16(const void* g, void* l){
  __builtin_amdgcn_global_load_lds(
      (const __attribute__((address_space(1))) unsigned int*)g,
      (__attribute__((address_space(3))) unsigned int*)l, 16, 0, 0);
}

#define VMW(n) asm volatile("s_waitcnt vmcnt(" #n ")" ::: "memory")

// ---------------------------------------------------------------- convert ---
// segments: x -> bf16 | [Wq;Wk;Wv] -> bf16 | Wo -> bf16 | spatial+edge -> bf16
// (measured ~15us = its HBM roofline: 94MB moved / 6.3 TB/s)
__global__ __launch_bounds__(256, 4) void k_convert(
    const float* __restrict__ x,  const float* __restrict__ sp,
    const float* __restrict__ ed, const float* __restrict__ wq,
    const float* __restrict__ wk, const float* __restrict__ wv,
    const float* __restrict__ wo,
    u16* __restrict__ xbf, u16* __restrict__ wqkv, u16* __restrict__ wob,
    u16* __restrict__ bsumb)
{
  const int NQX = TOK*HID/4;        // 1,572,864
  const int NQW = 3*HID*HID/4;      //   442,368
  const int NQO = HID*HID/4;        //   147,456
  int idx = blockIdx.x*256 + threadIdx.x;
  if (idx < NQX){
    int e = idx*4;
    float4 v = *(const float4*)(x+e);
    ushort4 o; o.x=f2bf(v.x); o.y=f2bf(v.y); o.z=f2bf(v.z); o.w=f2bf(v.w);
    *(ushort4*)(xbf+e) = o;
  } else if (idx < NQX+NQW){
    int e = (idx-NQX)*4;
    int row = e/HID, col = e%HID;
    const float* w = (row<768) ? (wq+row*HID)
                   : (row<1536 ? wk+(row-768)*HID : wv+(row-1536)*HID);
    float4 v = *(const float4*)(w+col);
    ushort4 o; o.x=f2bf(v.x); o.y=f2bf(v.y); o.z=f2bf(v.z); o.w=f2bf(v.w);
    *(ushort4*)(wqkv+e) = o;
  } else if (idx < NQX+NQW+NQO){
    int e = (idx-NQX-NQW)*4;
    float4 v = *(const float4*)(wo+e);
    ushort4 o; o.x=f2bf(v.x); o.y=f2bf(v.y); o.z=f2bf(v.z); o.w=f2bf(v.w);
    *(ushort4*)(wob+e) = o;
  } else {
    int e = (idx-NQX-NQW-NQO)*4;
    float4 a = *(const float4*)(sp+e);
    float4 b = *(const float4*)(ed+e);
    ushort4 o; o.x=f2bf(a.x+b.x); o.y=f2bf(a.y+b.y);
               o.z=f2bf(a.z+b.z); o.w=f2bf(a.w+b.w);
    *(ushort4*)(bsumb+e) = o;
  }
}

// -------------------------------------------------------------- fused QKV ---
// r15 fused QK+V^T, WIDENED: block = 128M x 256N, 4 waves (2x2), wave tile
// 64x128 -> acc[4][8], 32 MFMA per K-step per wave (2x r15) with 12 ds_reads
// (1.5x) -> barrier-rounds per FLOP halved (the per-step stall is ~constant;
// r7-attn's "2 tiles per staged chunk" lesson applied to the gemm). B-stage =
// two 128-col panels (4 gl_lds) + A (2) = 6/wave/stage; same proven 3-buffer
// depth-2 counted-vmcnt skeleton (steady VMW(6), tail VMW(0)@22). LDS 72KB ->
// 2 blocks/CU. Grid 576 = 8*72, XCD-chunked bijective swizzle; QK = 384
// logical blocks (6 N-pairs x 64 M), VT = 192 (32 token-pairs x 6 dd-tiles).
__global__ __launch_bounds__(256, 2) void k_qkv(
    const u16* __restrict__ xbf, const u16* __restrict__ wqkv,
    const float* __restrict__ bv,
    u16* __restrict__ qh, u16* __restrict__ kh, u16* __restrict__ vth)
{
  __shared__ u16 As[3][4096];    // 8KB/buf: 128 rows x 32 k (64B rows)
  __shared__ u16 Bs[3][8192];    // 16KB/buf: 256 rows x 32 k (64B rows)
  const int tid = threadIdx.x;
  const int wid = tid >> 6, lane = tid & 63;
  const int g = lane >> 4, c = lane & 15;
  const int wr = wid >> 1, wcn = wid & 1;   // wave tile 64M x 128N

  const int bid = blockIdx.x;                 // 576
  const int lg  = (bid & 7)*72 + (bid >> 3);  // XCD-chunked, bijective
  const bool isQK = lg < 384;

  const u16* Ap; const u16* Btp; long mbase; int nbase;
  if (isQK){
    int bx = lg % 6, by = lg / 6;             // 6 N-pairs x 64 M-tiles
    Ap = xbf; Btp = wqkv;
    mbase = (long)by * 128; nbase = bx * 256;
  } else {
    int lv = lg - 384;
    int bx = lv % 32, by = lv / 32;           // 32 token-256-tiles x 6 dd-128
    Ap = wqkv + 2*HID*HID; Btp = xbf;
    mbase = (long)by * 128; nbase = bx * 256;
  }

  f32x4 acc[4][8];
  #pragma unroll
  for (int i=0;i<4;i++)
    #pragma unroll
    for (int j=0;j<8;j++){ f32x4 z = {0.f,0.f,0.f,0.f}; acc[i][j] = z; }

  const char* Abase = (const char*)Ap  + mbase * HID * 2;
  const char* Bbase = (const char*)Btp + (long)nbase * HID * 2;

  const int L0 = wid*1024 + lane*16;         // A slots (8KB = 2 per thread)
  const int ar0 = L0 >> 6, ai0 = L0 & 63;
  const int L1 = L0 + 4096;
  const int ar1 = L1 >> 6, ai1 = L1 & 63;
  // B slots (16KB = 4 per thread)
  const int br0 = L0 >> 6,          bi0 = L0 & 63;
  const int br1 = (L0+4096) >> 6,   bi1 = bi0;
  const int br2 = (L0+8192) >> 6,   bi2 = bi0;
  const int br3 = (L0+12288) >> 6,  bi3 = bi0;

  // 6 gl_lds per wave per stage (A x2, B x4)
  #define GSTAGE(buf, kk) do { \
    gl_lds16(Abase + (long)ar0*1536 + (kk)*2 + ai0, (char*)As[buf] + wid*1024); \
    gl_lds16(Abase + (long)ar1*1536 + (kk)*2 + ai1, (char*)As[buf] + 4096 + wid*1024); \
    gl_lds16(Bbase + (long)br0*1536 + (kk)*2 + bi0, (char*)Bs[buf] + wid*1024); \
    gl_lds16(Bbase + (long)br1*1536 + (kk)*2 + bi1, (char*)Bs[buf] + 4096 + wid*1024); \
    gl_lds16(Bbase + (long)br2*1536 + (kk)*2 + bi2, (char*)Bs[buf] + 8192 + wid*1024); \
    gl_lds16(Bbase + (long)br3*1536 + (kk)*2 + bi3, (char*)Bs[buf] + 12288 + wid*1024); \
  } while(0)

  GSTAGE(0, 0);
  GSTAGE(1, 32);
  VMW(6);                       // stage0 landed (FIFO)
  __builtin_amdgcn_s_barrier();

  #pragma unroll 3
  for (int t = 0; t < 24; t++){
    if (t < 22) GSTAGE((t+2)%3, (t+2)*32);
    const char* Ab = (const char*)As[t%3];
    const char* Bb = (const char*)Bs[t%3];
    bf16x8 af[4], bfr[8];
    #pragma unroll
    for (int mt=0; mt<4; mt++){
      int row = wr*64 + mt*16 + c;
      af[mt] = *(const bf16x8*)(Ab + row*64 + g*16);
    }
    #pragma unroll
    for (int nt=0; nt<8; nt++){
      int row = wcn*128 + nt*16 + c;
      bfr[nt] = *(const bf16x8*)(Bb + row*64 + g*16);
    }
    __builtin_amdgcn_s_setprio(1);
    #pragma unroll
    for (int mt=0; mt<4; mt++)
      #pragma unroll
      for (int nt=0; nt<8; nt++)
        acc[mt][nt] = __builtin_amdgcn_mfma_f32_16x16x32_bf16(
            af[mt], bfr[nt], acc[mt][nt], 0,0,0);
    __builtin_amdgcn_s_setprio(0);
    if (t < 22)       VMW(6);
    else if (t == 22) VMW(0);
    if (t < 23) __builtin_amdgcn_s_barrier();
  }
  #undef GSTAGE

  if (isQK){
    #pragma unroll
    for (int nt=0; nt<8; nt++){
      int colg = nbase + wcn*128 + nt*16 + c;
      int region = colg >> 9 >= 1 && colg >= 768 ? 1 : 0;   // cols 0-767 Q, 768-1535 K
      int o = colg - region*768;
      int h = o >> 6, dd = o & 63;
      #pragma unroll
      for (int mt=0; mt<4; mt++)
        #pragma unroll
        for (int r=0;r<4;r++){
          long rowg = mbase + wr*64 + mt*16 + g*4 + r;
          int b = (int)(rowg >> 9), n = (int)(rowg & 511);
          long hb = (long)(b*NH + h);
          u16 val = f2bf(acc[mt][nt][r]);
          if (region==0) qh[(hb*SEQ + n)*HD + dd] = val;
          else           kh[(hb*SEQ + n)*HD + dd] = val;
        }
    }
  } else {  // V^T: rows = dd_global, cols = tokens; + bv[row]
    #pragma unroll
    for (int mt=0; mt<4; mt++){
      int rowg0 = (int)mbase + wr*64 + mt*16 + g*4;
      float4 bb = *(const float4*)(bv + rowg0);
      #pragma unroll
      for (int r=0;r<4;r++){
        int rowg = rowg0 + r;
        int h = rowg >> 6, dd = rowg & 63;
        float bv_ = r==0?bb.x : r==1?bb.y : r==2?bb.z : bb.w;
        #pragma unroll
        for (int nt=0; nt<8; nt++){
          int colg = nbase + wcn*128 + nt*16 + c;
          int b = colg >> 9, n = colg & 511;
          vth[((long)(b*NH + h)*HD + dd)*SEQ + n] = f2bf(acc[mt][nt][r] + bv_);
        }
      }
    }
  }
}

// ---------------------------------------------------------------- out-proj ---
// (r13/r15 structure: 3-buffer staging, depth-2 prefetch, counted vmcnt(4),
// T1 XCD swizzle; fp32 out + bo. Measured ~12us / 805 TF -- adequate.)
__global__ __launch_bounds__(256, 3) void k_gemmO(
    const u16* __restrict__ A, const u16* __restrict__ Bt,
    const float* __restrict__ bias, float* __restrict__ outf)
{
  __shared__ u16 As[3][4096];
  __shared__ u16 Bs[3][4096];
  const int tid = threadIdx.x;
  const int wid = tid >> 6, lane = tid & 63;
  const int g = lane >> 4, c = lane & 15;
  const int wr = wid >> 1, wc = wid & 1;

  const int nbx = gridDim.x;
  const int bid = blockIdx.x + nbx*blockIdx.y;
  const int cpx = (nbx*gridDim.y) >> 3;
  const int lg  = (bid & 7)*cpx + (bid >> 3);
  const int bx  = lg % nbx, by = lg / nbx;

  const long mbase = (long)by * 128;
  const int  nbase = bx * 128;

  f32x4 acc[4][4];
  #pragma unroll
  for (int i=0;i<4;i++)
    #pragma unroll
    for (int j=0;j<4;j++){ f32x4 z = {0.f,0.f,0.f,0.f}; acc[i][j] = z; }

  const char* Abase = (const char*)A  + mbase * HID * 2;
  const char* Bbase = (const char*)Bt + (long)nbase * HID * 2;

  const int L0 = wid*1024 + lane*16;
  const int ar0 = L0 >> 6, ai0 = L0 & 63;
  const int L1 = L0 + 4096;
  const int ar1 = L1 >> 6, ai1 = L1 & 63;

  #define GSTAGE(buf, kk) do { \
    gl_lds16(Abase + (long)ar0*1536 + (kk)*2 + ai0, (char*)As[buf] + wid*1024); \
    gl_lds16(Abase + (long)ar1*1536 + (kk)*2 + ai1, (char*)As[buf] + 4096 + wid*1024); \
    gl_lds16(Bbase + (long)ar0*1536 + (kk)*2 + ai0, (char*)Bs[buf] + wid*1024); \
    gl_lds16(Bbase + (long)ar1*1536 + (kk)*2 + ai1, (char*)Bs[buf] + 4096 + wid*1024); \
  } while(0)

  GSTAGE(0, 0);
  GSTAGE(1, 32);
  VMW(4);
  __builtin_amdgcn_s_barrier();

  #pragma unroll 3
  for (int t = 0; t < 24; t++){
    if (t < 22) GSTAGE((t+2)%3, (t+2)*32);
    const char* Ab = (const char*)As[t%3];
    const char* Bb = (const char*)Bs[t%3];
    bf16x8 af[4], bfr[4];
    #pragma unroll
    for (int mt=0; mt<4; mt++){
      int row = wr*64 + mt*16 + c;
      af[mt] = *(const bf16x8*)(Ab + row*64 + g*16);
    }
    #pragma unroll
    for (int nt=0; nt<4; nt++){
      int row = wc*64 + nt*16 + c;
      bfr[nt] = *(const bf16x8*)(Bb + row*64 + g*16);
    }
    #pragma unroll
    for (int mt=0; mt<4; mt++)
      #pragma unroll
      for (int nt=0; nt<4; nt++)
        acc[mt][nt] = __builtin_amdgcn_mfma_f32_16x16x32_bf16(
            af[mt], bfr[nt], acc[mt][nt], 0,0,0);
    if (t < 22)       VMW(4);
    else if (t == 22) VMW(0);
    if (t < 23) __builtin_amdgcn_s_barrier();
  }
  #undef GSTAGE

  #pragma unroll
  for (int nt=0; nt<4; nt++){
    int colg = nbase + wc*64 + nt*16 + c;
    float bb = bias[colg];
    #pragma unroll
    for (int mt=0; mt<4; mt++)
      #pragma unroll
      for (int r=0;r<4;r++){
        long rowg = mbase + wr*64 + mt*16 + g*4 + r;
        outf[rowg*HID + colg] = acc[mt][nt][r] + bb;
      }
  }
}

// ------------------------------------------------------------------- attn ---
// EXACT r9/r10/r13 kernel (measured 39.7 us; converged). 3-buffer K/V/BIAS
// staging, depth-2 prefetch, counted vmcnt(6) + raw s_barrier; bias staged
// via gl_lds; setprio around MFMA; swapped QK^T; no max-subtract;
// register-only P packs; rule-21 swizzle discipline.
__global__ __launch_bounds__(256, 2) void k_attn(
    const u16* __restrict__ Qh, const u16* __restrict__ Kh,
    const u16* __restrict__ VTh, const u16* __restrict__ bsumb,
    u16* __restrict__ attn)
{
  __shared__ u16 Ks[3][4096];   // 8KB/buf: row=k (64 x 128B), swizzled
  __shared__ u16 Vs[3][4096];   // 8KB/buf: row=d (64 x 128B), swizzled
  __shared__ u16 Bs[3][4096];   // 8KB/buf: row=q (64 x 128B), swizzled

  const int tid = threadIdx.x;
  const int wid = tid>>6, lane = tid&63, g = lane>>4, c = lane&15;
  const int L = (blockIdx.x & 7)*192 + (blockIdx.x >> 3);   // XCD-contiguous
  const int qt = L & 7, h = (L>>3) % 12, b = L/96;
  const u16*  Qp = Qh + (long)(b*NH+h)*SEQ*HD;
  const char* Kp = (const char*)(Kh  + (long)(b*NH+h)*SEQ*HD);
  const char* Vp = (const char*)(VTh + (long)(b*NH+h)*HD*SEQ);
  const char* Bp = (const char*)(bsumb + (long)b*SEQ*SEQ + (long)(qt*64)*SEQ);
  const int qbase = qt*64 + wid*16;

  bf16x8 qf0 = *(const bf16x8*)(Qp + (qbase + c)*HD +  0 + g*8);
  bf16x8 qf1 = *(const bf16x8*)(Qp + (qbase + c)*HD + 32 + g*8);

  const float scale = 0.036084391824351615f;   // 768^-0.5 (HIDDEN, not head)

  const int s0 = tid*16;
  const int r0 = s0>>7, i0 = (s0&127) ^ ((r0&7)<<4);
  const int s1 = s0 + 4096;
  const int r1 = s1>>7, i1 = (s1&127) ^ ((r1&7)<<4);

  // 6 gl_lds per wave per stage (K x2, V x2, bias x2)
  #define STAGE(buf, ch) do { \
    gl_lds16(Kp + (long)((ch)*64 + r0)*128 + i0, (char*)Ks[buf] + wid*1024); \
    gl_lds16(Kp + (long)((ch)*64 + r1)*128 + i1, (char*)Ks[buf] + wid*1024 + 4096); \
    gl_lds16(Vp + (long)r0*1024 + (ch)*128 + i0, (char*)Vs[buf] + wid*1024); \
    gl_lds16(Vp + (long)r1*1024 + (ch)*128 + i1, (char*)Vs[buf] + wid*1024 + 4096); \
    gl_lds16(Bp + (long)r0*1024 + (ch)*128 + i0, (char*)Bs[buf] + wid*1024); \
    gl_lds16(Bp + (long)r1*1024 + (ch)*128 + i1, (char*)Bs[buf] + wid*1024 + 4096); \
  } while(0)

  f32x4 o[4];
  #pragma unroll
  for (int dt=0;dt<4;dt++){ f32x4 z = {0.f,0.f,0.f,0.f}; o[dt]=z; }
  float l = 0.f;

  STAGE(0, 0);
  STAGE(1, 1);
  VMW(6);                               // stage0 landed (FIFO; Q also done)
  __builtin_amdgcn_s_barrier();

  #pragma unroll
  for (int ch=0; ch<8; ch++){
    if (ch < 6) STAGE((ch+2)%3, ch+2);  // depth-2 prefetch
    const char* Kb = (const char*)Ks[ch%3];
    const char* Vb = (const char*)Vs[ch%3];
    const char* Bb = (const char*)Bs[ch%3];
    const int brow = wid*16 + c, mBs = (c&7)<<4;
    u16x4 rb0 = *(const u16x4*)(Bb + brow*128 + (( 0 + g*8) ^ mBs));
    u16x4 rb1 = *(const u16x4*)(Bb + brow*128 + ((32 + g*8) ^ mBs));
    u16x4 rb2 = *(const u16x4*)(Bb + brow*128 + ((64 + g*8) ^ mBs));
    u16x4 rb3 = *(const u16x4*)(Bb + brow*128 + ((96 + g*8) ^ mBs));
    #pragma unroll
    for (int s=0; s<2; s++){
      const u16x4 rA = s ? rb2 : rb0;
      const u16x4 rB = s ? rb3 : rb1;
      const int rAi = s*32 + c, rBi = s*32 + 16 + c;
      const int mA = (rAi&7)<<4, mB = (rBi&7)<<4;
      bf16x8 ka0 = *(const bf16x8*)(Kb + rAi*128 + ((   g*16) ^ mA));
      bf16x8 ka1 = *(const bf16x8*)(Kb + rAi*128 + ((64+g*16) ^ mA));
      bf16x8 kb0 = *(const bf16x8*)(Kb + rBi*128 + ((   g*16) ^ mB));
      bf16x8 kb1 = *(const bf16x8*)(Kb + rBi*128 + ((64+g*16) ^ mB));
      f32x4 sA = {0.f,0.f,0.f,0.f}, sB = {0.f,0.f,0.f,0.f};
      __builtin_amdgcn_s_setprio(1);
      sA = __builtin_amdgcn_mfma_f32_16x16x32_bf16(ka0, qf0, sA, 0,0,0);
      sA = __builtin_amdgcn_mfma_f32_16x16x32_bf16(ka1, qf1, sA, 0,0,0);
      sB = __builtin_amdgcn_mfma_f32_16x16x32_bf16(kb0, qf0, sB, 0,0,0);
      sB = __builtin_amdgcn_mfma_f32_16x16x32_bf16(kb1, qf1, sB, 0,0,0);
      __builtin_amdgcn_s_setprio(0);
      float pA0 = __expf(fmaf(sA[0], scale, bf2f(rA[0])));
      float pA1 = __expf(fmaf(sA[1], scale, bf2f(rA[1])));
      float pA2 = __expf(fmaf(sA[2], scale, bf2f(rA[2])));
      float pA3 = __expf(fmaf(sA[3], scale, bf2f(rA[3])));
      float pB0 = __expf(fmaf(sB[0], scale, bf2f(rB[0])));
      float pB1 = __expf(fmaf(sB[1], scale, bf2f(rB[1])));
      float pB2 = __expf(fmaf(sB[2], scale, bf2f(rB[2])));
      float pB3 = __expf(fmaf(sB[3], scale, bf2f(rB[3])));
      l += ((pA0 + pA1) + (pA2 + pA3)) + ((pB0 + pB1) + (pB2 + pB3));
      u32x4 paw = { (unsigned)f2bf(pA0) | ((unsigned)f2bf(pA1) << 16),
                    (unsigned)f2bf(pA2) | ((unsigned)f2bf(pA3) << 16),
                    (unsigned)f2bf(pB0) | ((unsigned)f2bf(pB1) << 16),
                    (unsigned)f2bf(pB2) | ((unsigned)f2bf(pB3) << 16) };
      bf16x8 pav = __builtin_bit_cast(bf16x8, paw);
      __builtin_amdgcn_s_setprio(1);
      #pragma unroll
      for (int dt=0; dt<4; dt++){
        const int vr = dt*16 + c, mV = (vr&7)<<4;
        bf16x4 v0 = *(const bf16x4*)(Vb + vr*128 + ((s*64    + g*8) ^ mV));
        bf16x4 v1 = *(const bf16x4*)(Vb + vr*128 + ((s*64+32 + g*8) ^ mV));
        bf16x8 vbv = __builtin_shufflevector(v0, v1, 0,1,2,3,4,5,6,7);
        o[dt] = __builtin_amdgcn_mfma_f32_16x16x32_bf16(pav, vbv, o[dt], 0,0,0);
      }
      __builtin_amdgcn_s_setprio(0);
    }
    if (ch < 6)      VMW(6);
    else if (ch == 6) VMW(0);
    if (ch < 7) __builtin_amdgcn_s_barrier();
  }
  #undef STAGE

  l += __shfl_xor(l, 16, 64);
  l += __shfl_xor(l, 32, 64);
  float linv = 1.f / l;

  #pragma unroll
  for (int r=0;r<4;r++){
    float li = __shfl(linv, g*4 + r, 64);
    int q = qbase + g*4 + r;
    #pragma unroll
    for (int dt=0; dt<4; dt++)
      attn[(long)(b*SEQ + q)*HID + h*64 + dt*16 + c] = f2bf(o[dt][r] * li);
  }
}

// ----------------------------------------------------------------- launch ---
extern "C" void kernel_launch(void* const* d_in, const int* in_sizes, int n_in,
                              void* d_out, int out_size, void* d_ws, size_t ws_size,
                              hipStream_t stream)
{
  const float* x  = (const float*)d_in[0];
  const float* sp = (const float*)d_in[1];
  const float* ed = (const float*)d_in[2];
  const float* Wq = (const float*)d_in[3];
  const float* Wk = (const float*)d_in[4];
  const float* Wv = (const float*)d_in[5];
  const float* bv = (const float*)d_in[6];
  const float* Wo = (const float*)d_in[7];
  const float* bo = (const float*)d_in[8];
  float* out = (float*)d_out;

  u16* w = (u16*)d_ws;
  u16* xbf  = w;                      // 6,291,456 u16
  u16* wqkv = xbf  + TOK*HID;         // 1,769,472
  u16* wob  = wqkv + 3*HID*HID;       //   589,824
  u16* qh   = wob  + HID*HID;         // 6,291,456
  u16* kh   = qh   + TOK*HID;
  u16* vth  = kh   + TOK*HID;
  u16* attn = vth  + TOK*HID;
  u16* bsumb = attn + TOK*HID;        // 4,194,304 u16 (bf16 bias)

  k_convert<<<12544, 256, 0, stream>>>(x, sp, ed, Wq, Wk, Wv, Wo,
                                       xbf, wqkv, wob, bsumb);
  k_qkv<<<576, 256, 0, stream>>>(xbf, wqkv, bv, qh, kh, vth);
  k_attn<<<1536, 256, 0, stream>>>(qh, kh, vth, bsumb, attn);
  dim3 gO(6, 64);
  k_gemmO<<<gO, 256, 0, stream>>>(attn, wob, bo, out);
}

// Round 17
// 120.382 us; speedup vs baseline: 1.4486x; 1.4486x over previous
//
#include <hip/hip_runtime.h>

typedef unsigned short u16;
typedef short bf16x8 __attribute__((ext_vector_type(8)));
typedef short bf16x4 __attribute__((ext_vector_type(4)));
typedef float f32x4 __attribute__((ext_vector_type(4)));
typedef unsigned u32x4 __attribute__((ext_vector_type(4)));
typedef unsigned short u16x4 __attribute__((ext_vector_type(4)));

#define HID 768
#define NH  12
#define HD  64
#define BB  16
#define SEQ 512
#define TOK (BB*SEQ)   // 8192 tokens

static __device__ __forceinline__ u16 f2bf(float f){
  union { float f; unsigned u; } x; x.f = f;
  unsigned r = x.u + 0x7fffu + ((x.u >> 16) & 1u);   // RNE
  return (u16)(r >> 16);
}
static __device__ __forceinline__ float bf2f(u16 h){
  return __builtin_bit_cast(float, ((unsigned)h) << 16);
}

static __device__ __forceinline__ void gl_lds16(const void* g, void* l){
  __builtin_amdgcn_global_load_lds(
      (const __attribute__((address_space(1))) unsigned int*)g,
      (__attribute__((address_space(3))) unsigned int*)l, 16, 0, 0);
}

#define VMW(n) asm volatile("s_waitcnt vmcnt(" #n ")" ::: "memory")

// ---------------------------------------------------------------- convert ---
// segments: x -> bf16 | [Wq;Wk;Wv] -> bf16 | Wo -> bf16 | spatial+edge -> bf16
// (measured ~15us = its HBM roofline: ~94MB moved / 6.3 TB/s)
__global__ __launch_bounds__(256, 4) void k_convert(
    const float* __restrict__ x,  const float* __restrict__ sp,
    const float* __restrict__ ed, const float* __restrict__ wq,
    const float* __restrict__ wk, const float* __restrict__ wv,
    const float* __restrict__ wo,
    u16* __restrict__ xbf, u16* __restrict__ wqkv, u16* __restrict__ wob,
    u16* __restrict__ bsumb)
{
  const int NQX = TOK*HID/4;        // 1,572,864
  const int NQW = 3*HID*HID/4;      //   442,368
  const int NQO = HID*HID/4;        //   147,456
  int idx = blockIdx.x*256 + threadIdx.x;
  if (idx < NQX){
    int e = idx*4;
    float4 v = *(const float4*)(x+e);
    ushort4 o; o.x=f2bf(v.x); o.y=f2bf(v.y); o.z=f2bf(v.z); o.w=f2bf(v.w);
    *(ushort4*)(xbf+e) = o;
  } else if (idx < NQX+NQW){
    int e = (idx-NQX)*4;
    int row = e/HID, col = e%HID;
    const float* w = (row<768) ? (wq+row*HID)
                   : (row<1536 ? wk+(row-768)*HID : wv+(row-1536)*HID);
    float4 v = *(const float4*)(w+col);
    ushort4 o; o.x=f2bf(v.x); o.y=f2bf(v.y); o.z=f2bf(v.z); o.w=f2bf(v.w);
    *(ushort4*)(wqkv+e) = o;
  } else if (idx < NQX+NQW+NQO){
    int e = (idx-NQX-NQW)*4;
    float4 v = *(const float4*)(wo+e);
    ushort4 o; o.x=f2bf(v.x); o.y=f2bf(v.y); o.z=f2bf(v.z); o.w=f2bf(v.w);
    *(ushort4*)(wob+e) = o;
  } else {
    int e = (idx-NQX-NQW-NQO)*4;
    float4 a = *(const float4*)(sp+e);
    float4 b = *(const float4*)(ed+e);
    ushort4 o; o.x=f2bf(a.x+b.x); o.y=f2bf(a.y+b.y);
               o.z=f2bf(a.z+b.z); o.w=f2bf(a.w+b.w);
    *(ushort4*)(bsumb+e) = o;
  }
}

// -------------------------------------------------------------- fused QKV ---
// EXACT r15 structure (measured 53.9us; r16's 256-wide variant halved
// residency and DOUBLED dur -- widening is 4-for-4 negative on this op).
// QK-proj (768 logical blocks) + V^T-proj (384) fused into one 1152-block
// dispatch; 3-buffer gl_lds staging of A and B, depth-2 prefetch, counted
// vmcnt(4) + raw s_barrier. NEW vs r15: T5 setprio around the MFMA cluster
// (pure addition; counted-vmcnt schedule => waves at different micro-phases,
// m218b regime).
__global__ __launch_bounds__(256, 3) void k_qkv(
    const u16* __restrict__ xbf, const u16* __restrict__ wqkv,
    const float* __restrict__ bv,
    u16* __restrict__ qh, u16* __restrict__ kh, u16* __restrict__ vth)
{
  __shared__ u16 As[3][4096];
  __shared__ u16 Bs[3][4096];
  const int tid = threadIdx.x;
  const int wid = tid >> 6, lane = tid & 63;
  const int g = lane >> 4, c = lane & 15;
  const int wr = wid >> 1, wc = wid & 1;

  const int bid = blockIdx.x;                 // 1152
  const int lg  = (bid & 7)*144 + (bid >> 3); // XCD-chunked, bijective
  const bool isQK = lg < 768;

  const u16* Ap; const u16* Btp; long mbase; int nbase;
  if (isQK){
    int bx = lg % 12, by = lg / 12;           // 12 N-tiles x 64 M-tiles
    Ap = xbf; Btp = wqkv;
    mbase = (long)by * 128; nbase = bx * 128;
  } else {
    int lv = lg - 768;
    int bx = lv % 64, by = lv / 64;           // 64 token-tiles x 6 dd-tiles
    Ap = wqkv + 2*HID*HID; Btp = xbf;
    mbase = (long)by * 128; nbase = bx * 128;
  }

  f32x4 acc[4][4];
  #pragma unroll
  for (int i=0;i<4;i++)
    #pragma unroll
    for (int j=0;j<4;j++){ f32x4 z = {0.f,0.f,0.f,0.f}; acc[i][j] = z; }

  const char* Abase = (const char*)Ap  + mbase * HID * 2;
  const char* Bbase = (const char*)Btp + (long)nbase * HID * 2;

  const int L0 = wid*1024 + lane*16;
  const int ar0 = L0 >> 6, ai0 = L0 & 63;
  const int L1 = L0 + 4096;
  const int ar1 = L1 >> 6, ai1 = L1 & 63;

  #define GSTAGE(buf, kk) do { \
    gl_lds16(Abase + (long)ar0*1536 + (kk)*2 + ai0, (char*)As[buf] + wid*1024); \
    gl_lds16(Abase + (long)ar1*1536 + (kk)*2 + ai1, (char*)As[buf] + 4096 + wid*1024); \
    gl_lds16(Bbase + (long)ar0*1536 + (kk)*2 + ai0, (char*)Bs[buf] + wid*1024); \
    gl_lds16(Bbase + (long)ar1*1536 + (kk)*2 + ai1, (char*)Bs[buf] + 4096 + wid*1024); \
  } while(0)

  GSTAGE(0, 0);
  GSTAGE(1, 32);
  VMW(4);
  __builtin_amdgcn_s_barrier();

  #pragma unroll 3
  for (int t = 0; t < 24; t++){
    if (t < 22) GSTAGE((t+2)%3, (t+2)*32);
    const char* Ab = (const char*)As[t%3];
    const char* Bb = (const char*)Bs[t%3];
    bf16x8 af[4], bfr[4];
    #pragma unroll
    for (int mt=0; mt<4; mt++){
      int row = wr*64 + mt*16 + c;
      af[mt] = *(const bf16x8*)(Ab + row*64 + g*16);
    }
    #pragma unroll
    for (int nt=0; nt<4; nt++){
      int row = wc*64 + nt*16 + c;
      bfr[nt] = *(const bf16x8*)(Bb + row*64 + g*16);
    }
    __builtin_amdgcn_s_setprio(1);
    #pragma unroll
    for (int mt=0; mt<4; mt++)
      #pragma unroll
      for (int nt=0; nt<4; nt++)
        acc[mt][nt] = __builtin_amdgcn_mfma_f32_16x16x32_bf16(
            af[mt], bfr[nt], acc[mt][nt], 0,0,0);
    __builtin_amdgcn_s_setprio(0);
    if (t < 22)       VMW(4);
    else if (t == 22) VMW(0);
    if (t < 23) __builtin_amdgcn_s_barrier();
  }
  #undef GSTAGE

  if (isQK){
    int region = (nbase >> 7) / 6;   // 12 col-tiles: 0-5 Q, 6-11 K
    #pragma unroll
    for (int nt=0; nt<4; nt++){
      int colg = nbase + wc*64 + nt*16 + c;
      int o = colg - region*768;
      int h = o >> 6, dd = o & 63;
      #pragma unroll
      for (int mt=0; mt<4; mt++)
        #pragma unroll
        for (int r=0;r<4;r++){
          long rowg = mbase + wr*64 + mt*16 + g*4 + r;
          int b = (int)(rowg >> 9), n = (int)(rowg & 511);
          long hb = (long)(b*NH + h);
          u16 val = f2bf(acc[mt][nt][r]);
          if (region==0) qh[(hb*SEQ + n)*HD + dd] = val;
          else           kh[(hb*SEQ + n)*HD + dd] = val;
        }
    }
  } else {  // V^T: rows = dd_global, cols = tokens; + bv[row]
    #pragma unroll
    for (int mt=0; mt<4; mt++){
      int rowg0 = (int)mbase + wr*64 + mt*16 + g*4;
      float4 bb = *(const float4*)(bv + rowg0);
      #pragma unroll
      for (int r=0;r<4;r++){
        int rowg = rowg0 + r;
        int h = rowg >> 6, dd = rowg & 63;
        float bv_ = r==0?bb.x : r==1?bb.y : r==2?bb.z : bb.w;
        #pragma unroll
        for (int nt=0; nt<4; nt++){
          int colg = nbase + wc*64 + nt*16 + c;
          int b = colg >> 9, n = colg & 511;
          vth[((long)(b*NH + h)*HD + dd)*SEQ + n] = f2bf(acc[mt][nt][r] + bv_);
        }
      }
    }
  }
}

// ---------------------------------------------------------------- out-proj ---
// (r13/r15 structure + T5 setprio; 3-buffer staging, depth-2 prefetch,
// counted vmcnt(4), T1 XCD swizzle; fp32 out + bo.)
__global__ __launch_bounds__(256, 3) void k_gemmO(
    const u16* __restrict__ A, const u16* __restrict__ Bt,
    const float* __restrict__ bias, float* __restrict__ outf)
{
  __shared__ u16 As[3][4096];
  __shared__ u16 Bs[3][4096];
  const int tid = threadIdx.x;
  const int wid = tid >> 6, lane = tid & 63;
  const int g = lane >> 4, c = lane & 15;
  const int wr = wid >> 1, wc = wid & 1;

  const int nbx = gridDim.x;
  const int bid = blockIdx.x + nbx*blockIdx.y;
  const int cpx = (nbx*gridDim.y) >> 3;
  const int lg  = (bid & 7)*cpx + (bid >> 3);
  const int bx  = lg % nbx, by = lg / nbx;

  const long mbase = (long)by * 128;
  const int  nbase = bx * 128;

  f32x4 acc[4][4];
  #pragma unroll
  for (int i=0;i<4;i++)
    #pragma unroll
    for (int j=0;j<4;j++){ f32x4 z = {0.f,0.f,0.f,0.f}; acc[i][j] = z; }

  const char* Abase = (const char*)A  + mbase * HID * 2;
  const char* Bbase = (const char*)Bt + (long)nbase * HID * 2;

  const int L0 = wid*1024 + lane*16;
  const int ar0 = L0 >> 6, ai0 = L0 & 63;
  const int L1 = L0 + 4096;
  const int ar1 = L1 >> 6, ai1 = L1 & 63;

  #define GSTAGE(buf, kk) do { \
    gl_lds16(Abase + (long)ar0*1536 + (kk)*2 + ai0, (char*)As[buf] + wid*1024); \
    gl_lds16(Abase + (long)ar1*1536 + (kk)*2 + ai1, (char*)As[buf] + 4096 + wid*1024); \
    gl_lds16(Bbase + (long)ar0*1536 + (kk)*2 + ai0, (char*)Bs[buf] + wid*1024); \
    gl_lds16(Bbase + (long)ar1*1536 + (kk)*2 + ai1, (char*)Bs[buf] + 4096 + wid*1024); \
  } while(0)

  GSTAGE(0, 0);
  GSTAGE(1, 32);
  VMW(4);
  __builtin_amdgcn_s_barrier();

  #pragma unroll 3
  for (int t = 0; t < 24; t++){
    if (t < 22) GSTAGE((t+2)%3, (t+2)*32);
    const char* Ab = (const char*)As[t%3];
    const char* Bb = (const char*)Bs[t%3];
    bf16x8 af[4], bfr[4];
    #pragma unroll
    for (int mt=0; mt<4; mt++){
      int row = wr*64 + mt*16 + c;
      af[mt] = *(const bf16x8*)(Ab + row*64 + g*16);
    }
    #pragma unroll
    for (int nt=0; nt<4; nt++){
      int row = wc*64 + nt*16 + c;
      bfr[nt] = *(const bf16x8*)(Bb + row*64 + g*16);
    }
    __builtin_amdgcn_s_setprio(1);
    #pragma unroll
    for (int mt=0; mt<4; mt++)
      #pragma unroll
      for (int nt=0; nt<4; nt++)
        acc[mt][nt] = __builtin_amdgcn_mfma_f32_16x16x32_bf16(
            af[mt], bfr[nt], acc[mt][nt], 0,0,0);
    __builtin_amdgcn_s_setprio(0);
    if (t < 22)       VMW(4);
    else if (t == 22) VMW(0);
    if (t < 23) __builtin_amdgcn_s_barrier();
  }
  #undef GSTAGE

  #pragma unroll
  for (int nt=0; nt<4; nt++){
    int colg = nbase + wc*64 + nt*16 + c;
    float bb = bias[colg];
    #pragma unroll
    for (int mt=0; mt<4; mt++)
      #pragma unroll
      for (int r=0;r<4;r++){
        long rowg = mbase + wr*64 + mt*16 + g*4 + r;
        outf[rowg*HID + colg] = acc[mt][nt][r] + bb;
      }
  }
}

// ------------------------------------------------------------------- attn ---
// EXACT r9/r10/r13/r15 kernel (measured 39.7 us; converged). 3-buffer
// K/V/BIAS staging, depth-2 prefetch, counted vmcnt(6) + raw s_barrier; bias
// staged via gl_lds; setprio around MFMA; swapped QK^T; no max-subtract;
// register-only P packs; rule-21 swizzle discipline.
__global__ __launch_bounds__(256, 2) void k_attn(
    const u16* __restrict__ Qh, const u16* __restrict__ Kh,
    const u16* __restrict__ VTh, const u16* __restrict__ bsumb,
    u16* __restrict__ attn)
{
  __shared__ u16 Ks[3][4096];   // 8KB/buf: row=k (64 x 128B), swizzled
  __shared__ u16 Vs[3][4096];   // 8KB/buf: row=d (64 x 128B), swizzled
  __shared__ u16 Bs[3][4096];   // 8KB/buf: row=q (64 x 128B), swizzled

  const int tid = threadIdx.x;
  const int wid = tid>>6, lane = tid&63, g = lane>>4, c = lane&15;
  const int L = (blockIdx.x & 7)*192 + (blockIdx.x >> 3);   // XCD-contiguous
  const int qt = L & 7, h = (L>>3) % 12, b = L/96;
  const u16*  Qp = Qh + (long)(b*NH+h)*SEQ*HD;
  const char* Kp = (const char*)(Kh  + (long)(b*NH+h)*SEQ*HD);
  const char* Vp = (const char*)(VTh + (long)(b*NH+h)*HD*SEQ);
  const char* Bp = (const char*)(bsumb + (long)b*SEQ*SEQ + (long)(qt*64)*SEQ);
  const int qbase = qt*64 + wid*16;

  bf16x8 qf0 = *(const bf16x8*)(Qp + (qbase + c)*HD +  0 + g*8);
  bf16x8 qf1 = *(const bf16x8*)(Qp + (qbase + c)*HD + 32 + g*8);

  const float scale = 0.036084391824351615f;   // 768^-0.5 (HIDDEN, not head)

  const int s0 = tid*16;
  const int r0 = s0>>7, i0 = (s0&127) ^ ((r0&7)<<4);
  const int s1 = s0 + 4096;
  const int r1 = s1>>7, i1 = (s1&127) ^ ((r1&7)<<4);

  // 6 gl_lds per wave per stage (K x2, V x2, bias x2)
  #define STAGE(buf, ch) do { \
    gl_lds16(Kp + (long)((ch)*64 + r0)*128 + i0, (char*)Ks[buf] + wid*1024); \
    gl_lds16(Kp + (long)((ch)*64 + r1)*128 + i1, (char*)Ks[buf] + wid*1024 + 4096); \
    gl_lds16(Vp + (long)r0*1024 + (ch)*128 + i0, (char*)Vs[buf] + wid*1024); \
    gl_lds16(Vp + (long)r1*1024 + (ch)*128 + i1, (char*)Vs[buf] + wid*1024 + 4096); \
    gl_lds16(Bp + (long)r0*1024 + (ch)*128 + i0, (char*)Bs[buf] + wid*1024); \
    gl_lds16(Bp + (long)r1*1024 + (ch)*128 + i1, (char*)Bs[buf] + wid*1024 + 4096); \
  } while(0)

  f32x4 o[4];
  #pragma unroll
  for (int dt=0;dt<4;dt++){ f32x4 z = {0.f,0.f,0.f,0.f}; o[dt]=z; }
  float l = 0.f;

  STAGE(0, 0);
  STAGE(1, 1);
  VMW(6);                               // stage0 landed (FIFO; Q also done)
  __builtin_amdgcn_s_barrier();

  #pragma unroll
  for (int ch=0; ch<8; ch++){
    if (ch < 6) STAGE((ch+2)%3, ch+2);  // depth-2 prefetch
    const char* Kb = (const char*)Ks[ch%3];
    const char* Vb = (const char*)Vs[ch%3];
    const char* Bb = (const char*)Bs[ch%3];
    const int brow = wid*16 + c, mBs = (c&7)<<4;
    u16x4 rb0 = *(const u16x4*)(Bb + brow*128 + (( 0 + g*8) ^ mBs));
    u16x4 rb1 = *(const u16x4*)(Bb + brow*128 + ((32 + g*8) ^ mBs));
    u16x4 rb2 = *(const u16x4*)(Bb + brow*128 + ((64 + g*8) ^ mBs));
    u16x4 rb3 = *(const u16x4*)(Bb + brow*128 + ((96 + g*8) ^ mBs));
    #pragma unroll
    for (int s=0; s<2; s++){
      const u16x4 rA = s ? rb2 : rb0;
      const u16x4 rB = s ? rb3 : rb1;
      const int rAi = s*32 + c, rBi = s*32 + 16 + c;
      const int mA = (rAi&7)<<4, mB = (rBi&7)<<4;
      bf16x8 ka0 = *(const bf16x8*)(Kb + rAi*128 + ((   g*16) ^ mA));
      bf16x8 ka1 = *(const bf16x8*)(Kb + rAi*128 + ((64+g*16) ^ mA));
      bf16x8 kb0 = *(const bf16x8*)(Kb + rBi*128 + ((   g*16) ^ mB));
      bf16x8 kb1 = *(const bf16x8*)(Kb + rBi*128 + ((64+g*16) ^ mB));
      f32x4 sA = {0.f,0.f,0.f,0.f}, sB = {0.f,0.f,0.f,0.f};
      __builtin_amdgcn_s_setprio(1);
      sA = __builtin_amdgcn_mfma_f32_16x16x32_bf16(ka0, qf0, sA, 0,0,0);
      sA = __builtin_amdgcn_mfma_f32_16x16x32_bf16(ka1, qf1, sA, 0,0,0);
      sB = __builtin_amdgcn_mfma_f32_16x16x32_bf16(kb0, qf0, sB, 0,0,0);
      sB = __builtin_amdgcn_mfma_f32_16x16x32_bf16(kb1, qf1, sB, 0,0,0);
      __builtin_amdgcn_s_setprio(0);
      float pA0 = __expf(fmaf(sA[0], scale, bf2f(rA[0])));
      float pA1 = __expf(fmaf(sA[1], scale, bf2f(rA[1])));
      float pA2 = __expf(fmaf(sA[2], scale, bf2f(rA[2])));
      float pA3 = __expf(fmaf(sA[3], scale, bf2f(rA[3])));
      float pB0 = __expf(fmaf(sB[0], scale, bf2f(rB[0])));
      float pB1 = __expf(fmaf(sB[1], scale, bf2f(rB[1])));
      float pB2 = __expf(fmaf(sB[2], scale, bf2f(rB[2])));
      float pB3 = __expf(fmaf(sB[3], scale, bf2f(rB[3])));
      l += ((pA0 + pA1) + (pA2 + pA3)) + ((pB0 + pB1) + (pB2 + pB3));
      u32x4 paw = { (unsigned)f2bf(pA0) | ((unsigned)f2bf(pA1) << 16),
                    (unsigned)f2bf(pA2) | ((unsigned)f2bf(pA3) << 16),
                    (unsigned)f2bf(pB0) | ((unsigned)f2bf(pB1) << 16),
                    (unsigned)f2bf(pB2) | ((unsigned)f2bf(pB3) << 16) };
      bf16x8 pav = __builtin_bit_cast(bf16x8, paw);
      __builtin_amdgcn_s_setprio(1);
      #pragma unroll
      for (int dt=0; dt<4; dt++){
        const int vr = dt*16 + c, mV = (vr&7)<<4;
        bf16x4 v0 = *(const bf16x4*)(Vb + vr*128 + ((s*64    + g*8) ^ mV));
        bf16x4 v1 = *(const bf16x4*)(Vb + vr*128 + ((s*64+32 + g*8) ^ mV));
        bf16x8 vbv = __builtin_shufflevector(v0, v1, 0,1,2,3,4,5,6,7);
        o[dt] = __builtin_amdgcn_mfma_f32_16x16x32_bf16(pav, vbv, o[dt], 0,0,0);
      }
      __builtin_amdgcn_s_setprio(0);
    }
    if (ch < 6)      VMW(6);
    else if (ch == 6) VMW(0);
    if (ch < 7) __builtin_amdgcn_s_barrier();
  }
  #undef STAGE

  l += __shfl_xor(l, 16, 64);
  l += __shfl_xor(l, 32, 64);
  float linv = 1.f / l;

  #pragma unroll
  for (int r=0;r<4;r++){
    float li = __shfl(linv, g*4 + r, 64);
    int q = qbase + g*4 + r;
    #pragma unroll
    for (int dt=0; dt<4; dt++)
      attn[(long)(b*SEQ + q)*HID + h*64 + dt*16 + c] = f2bf(o[dt][r] * li);
  }
}

// ----------------------------------------------------------------- launch ---
extern "C" void kernel_launch(void* const* d_in, const int* in_sizes, int n_in,
                              void* d_out, int out_size, void* d_ws, size_t ws_size,
                              hipStream_t stream)
{
  const float* x  = (const float*)d_in[0];
  const float* sp = (const float*)d_in[1];
  const float* ed = (const float*)d_in[2];
  const float* Wq = (const float*)d_in[3];
  const float* Wk = (const float*)d_in[4];
  const float* Wv = (const float*)d_in[5];
  const float* bv = (const float*)d_in[6];
  const float* Wo = (const float*)d_in[7];
  const float* bo = (const float*)d_in[8];
  float* out = (float*)d_out;

  u16* w = (u16*)d_ws;
  u16* xbf  = w;                      // 6,291,456 u16
  u16* wqkv = xbf  + TOK*HID;         // 1,769,472
  u16* wob  = wqkv + 3*HID*HID;       //   589,824
  u16* qh   = wob  + HID*HID;         // 6,291,456
  u16* kh   = qh   + TOK*HID;
  u16* vth  = kh   + TOK*HID;
  u16* attn = vth  + TOK*HID;
  u16* bsumb = attn + TOK*HID;        // 4,194,304 u16 (bf16 bias)

  k_convert<<<12544, 256, 0, stream>>>(x, sp, ed, Wq, Wk, Wv, Wo,
                                       xbf, wqkv, wob, bsumb);
  k_qkv<<<1152, 256, 0, stream>>>(xbf, wqkv, bv, qh, kh, vth);
  k_attn<<<1536, 256, 0, stream>>>(qh, kh, vth, bsumb, attn);
  dim3 gO(6, 64);
  k_gemmO<<<gO, 256, 0, stream>>>(attn, wob, bo, out);
}